// Round 7
// baseline (309.268 us; speedup 1.0000x reference)
//
#include <hip/hip_runtime.h>
#include <hip/hip_bf16.h>

#define N_NODES 8192
#define D_IN 32
#define N3 6144
#define N2 4096
#define N1 2048
#define N0 1024
#define NE 16384
#define KSL 16          // k-slices (split-K factor)
#define KS  (N_NODES / KSL)

// ---------------------------------------------------------------------------
// zero_ws: vectorized zero-fill of the accumulation region. Replaces
// hipMemsetAsync, whose fill kernel ran at 61 GB/s (152 us for 9.3 MB —
// half of round-6's total time).
// ---------------------------------------------------------------------------
__global__ void zero_ws(float4* __restrict__ p, int n4) {
    int idx = blockIdx.x * 256 + threadIdx.x;
    int stride = gridDim.x * 256;
    float4 z = {0.f, 0.f, 0.f, 0.f};
    for (int i = idx; i < n4; i += stride) p[i] = z;
}

// ---------------------------------------------------------------------------
// index conversion (verified: inputs are int64) + structural canary bits
// ---------------------------------------------------------------------------
__global__ void convert_idx(const void* __restrict__ nraw, const void* __restrict__ eraw,
                            int* __restrict__ n32, int* __restrict__ s32,
                            int* __restrict__ flags) {
    int idx = blockIdx.x * 256 + threadIdx.x;
    const int* ni = (const int*)nraw;
    const long long* nl = (const long long*)nraw;
    const int* ei = (const int*)eraw;
    const long long* el = (const long long*)eraw;
    bool n64 = true, e64 = true;
#pragma unroll
    for (int j = 0; j < 8; ++j) {
        long long a = nl[j]; if (a < 0 || a >= N_NODES) n64 = false;
        long long b = el[j]; if (b < 0 || b >= N1)      e64 = false;
    }
    if (idx < N3) {
        int v = n64 ? (int)nl[idx] : ni[idx];
        n32[idx] = v;
        if (v < 0 || v >= N_NODES) atomicOr(flags, 2);
    }
    if (idx < NE) {
        int v = e64 ? (int)el[idx] : ei[idx];
        s32[idx] = v;
        if (v < 0 || v >= N1) atomicOr(flags, 4);
        int d = e64 ? (int)el[NE + idx] : ei[NE + idx];
        if (d != (idx >> 4)) atomicOr(flags, 8);
    }
}

__global__ void count_kernel(const int* __restrict__ n32,
                             int* __restrict__ cntA, int* __restrict__ cntB,
                             int* __restrict__ cntC) {
    int j = blockIdx.x * blockDim.x + threadIdx.x;
    if (j >= N3) return;
    int c = n32[j];
    atomicAdd(&cntA[c], 1);
    if (j < N2) atomicAdd(&cntB[c], 1);
    if (j < N1) atomicAdd(&cntC[c], 1);
}

__global__ void compact_kernel(const int* __restrict__ cntA, const int* __restrict__ cntB,
                               const int* __restrict__ cntC, int* __restrict__ listA,
                               int* __restrict__ listB, int* __restrict__ listC,
                               int* __restrict__ nptr) {
    int c = blockIdx.x * 256 + threadIdx.x;
    if (c >= N_NODES) return;
    if (cntA[c]) listA[atomicAdd(&nptr[0], 1)] = c;
    if (cntB[c]) listB[atomicAdd(&nptr[1], 1)] = c;
    if (cntC[c]) listC[atomicAdd(&nptr[2], 1)] = c;
}

// ---------------------------------------------------------------------------
// fp32 split-K row-compacted matmul (harness-verified rounds 5-6).
// Block = 64 listed rows x NC cols x KS-wide k-slice; 256 thr as 16x16;
// thread tile 4 rows x CT cols. Partials atomicAdd into zeroed buffers.
// MODE 0: part=pA [8192][32]               (grid.z=1, Kmat=L)
// MODE 1: part=g1 [8192][64], zoff=z*32    (grid.z=2, K0/K1)
// MODE 2: part=g2 [8192][128], zoff=z*64   (grid.z=2, K0/K1)
// ---------------------------------------------------------------------------
template <int NC, int MODE>
__global__ __launch_bounds__(256) void rows_f32s(
    const float* __restrict__ Kmat0, const float* __restrict__ Kmat1,
    const float* __restrict__ B, const int* __restrict__ list,
    const int* __restrict__ nptr, int nidx, float* __restrict__ part) {
    constexpr int CK = 64;
    constexpr int CT = NC / 16;
    constexpr int NCTOT = (MODE == 0) ? 32 : ((MODE == 1) ? 64 : 128);
    __shared__ float Alds[64][CK + 4];
    __shared__ float Blds[CK][NC];
    __shared__ int rows_s[64];

    const int nrows = nptr[nidx];
    const int c0 = blockIdx.x * 64;
    if (c0 >= nrows) return;
    const int kb = blockIdx.y * KS;
    const int tid = threadIdx.x;
    const int tx = tid & 15;
    const int ty = tid >> 4;
    const float* Kmat = (blockIdx.z == 0) ? Kmat0 : Kmat1;
    const int zoff = (MODE == 0) ? 0 : (int)blockIdx.z * NC;

    if (tid < 64) {
        int li = c0 + tid;
        rows_s[tid] = (li < nrows) ? list[li] : -1;
    }
    __syncthreads();

    float acc[4][CT];
#pragma unroll
    for (int i = 0; i < 4; ++i)
#pragma unroll
        for (int j = 0; j < CT; ++j) acc[i][j] = 0.0f;

    const int ar = tid >> 2, aq = tid & 3;
    const int crow = rows_s[ar];

    for (int k0 = 0; k0 < KS; k0 += CK) {
        if (crow >= 0) {
            const float4* src =
                (const float4*)(Kmat + (size_t)crow * N_NODES + kb + k0 + aq * 16);
#pragma unroll
            for (int m = 0; m < 4; ++m) *(float4*)&Alds[ar][aq * 16 + 4 * m] = src[m];
        } else {
            float4 zz = {0.f, 0.f, 0.f, 0.f};
#pragma unroll
            for (int m = 0; m < 4; ++m) *(float4*)&Alds[ar][aq * 16 + 4 * m] = zz;
        }
        {
            const float4* bs = (const float4*)(B + (size_t)(kb + k0) * NC);
            float4* bl = (float4*)&Blds[0][0];
#pragma unroll
            for (int i = 0; i < CK * NC / 4 / 256; ++i) bl[tid + 256 * i] = bs[tid + 256 * i];
        }
        __syncthreads();
#pragma unroll 4
        for (int k = 0; k < CK; ++k) {
            float a0 = Alds[4 * ty + 0][k];
            float a1 = Alds[4 * ty + 1][k];
            float a2 = Alds[4 * ty + 2][k];
            float a3 = Alds[4 * ty + 3][k];
            float b[CT];
            if constexpr (CT == 4) {
                float4 bb = *(const float4*)&Blds[k][tx * 4];
                b[0] = bb.x; b[1] = bb.y; b[2] = bb.z; b[3] = bb.w;
            } else {
                float2 bb = *(const float2*)&Blds[k][tx * 2];
                b[0] = bb.x; b[1] = bb.y;
            }
#pragma unroll
            for (int j = 0; j < CT; ++j) {
                acc[0][j] = fmaf(a0, b[j], acc[0][j]);
                acc[1][j] = fmaf(a1, b[j], acc[1][j]);
                acc[2][j] = fmaf(a2, b[j], acc[2][j]);
                acc[3][j] = fmaf(a3, b[j], acc[3][j]);
            }
        }
        __syncthreads();
    }

#pragma unroll
    for (int i = 0; i < 4; ++i) {
        int c = rows_s[4 * ty + i];
        if (c < 0) continue;
#pragma unroll
        for (int j = 0; j < CT; ++j)
            atomicAdd(&part[(size_t)c * NCTOT + zoff + tx * CT + j], acc[i][j]);
    }
}

// epilogue 0: uA = cntA * (x - tau * pA)  (in place over pA)
__global__ void ep0_kernel(const float* __restrict__ x, const float* __restrict__ tau_p,
                           const int* __restrict__ cntA, float* __restrict__ uA) {
    int idx = blockIdx.x * 256 + threadIdx.x;
    if (idx >= N_NODES * 32) return;
    int c = idx >> 5;
    uA[idx] = (float)cntA[c] * (x[idx] - tau_p[0] * uA[idx]);
}

// epilogue 1: uB = cntB * g1
__global__ void ep1_kernel(const int* __restrict__ cntB, const float* __restrict__ g1,
                           float* __restrict__ uB) {
    int idx = blockIdx.x * 256 + threadIdx.x;
    if (idx >= N_NODES * 64) return;
    int c = idx >> 6;
    uB[idx] = (float)cntB[c] * g1[idx];
}

// z[i, 0:192] = [ g1[n32[i], 0:64] | g2[n32[i], 0:128] ]
__global__ void z_kernel(const float* __restrict__ g1, const float* __restrict__ g2,
                         const int* __restrict__ n32, float* __restrict__ z) {
    int idx = blockIdx.x * 256 + threadIdx.x;
    if (idx >= N1 * 192) return;
    int i = idx / 192, d = idx % 192;
    int c = n32[i];
    z[idx] = (d < 64) ? g1[(size_t)c * 64 + d] : g2[(size_t)c * 128 + (d - 64)];
}

// SAGE conv + MLP head (dst == repeat(arange(1024),16), canary-verified)
__global__ void head_kernel(const float* __restrict__ z, const int* __restrict__ s32,
                            const float* __restrict__ Wself, const float* __restrict__ Wneigh,
                            const float* __restrict__ bconv, const float* __restrict__ W1,
                            const float* __restrict__ b1, const float* __restrict__ W2,
                            const float* __restrict__ b2, float* __restrict__ out) {
    __shared__ float zs[192], za[192], hc[128], hm[64];
    __shared__ int srcs[16];
    int t = threadIdx.x, b = blockIdx.x;
    if (t < 16) srcs[t] = s32[b * 16 + t];
    __syncthreads();
    if (t < 192) {
        zs[t] = z[(size_t)b * 192 + t];
        float s = 0.f;
#pragma unroll
        for (int e = 0; e < 16; ++e) s += z[(size_t)srcs[e] * 192 + t];
        za[t] = s * (1.0f / 16.0f);
    }
    __syncthreads();
    if (t < 128) {
        float s = bconv[t];
        for (int d = 0; d < 192; ++d)
            s += zs[d] * Wself[d * 128 + t] + za[d] * Wneigh[d * 128 + t];
        hc[t] = s;
    }
    __syncthreads();
    if (t < 64) {
        float s = b1[t];
        for (int h = 0; h < 128; ++h) s += hc[h] * W1[h * 64 + t];
        hm[t] = fmaxf(s, 0.0f);
    }
    __syncthreads();
    if (t < 32) {
        float s = b2[t];
        for (int j = 0; j < 64; ++j) s += hm[j] * W2[j * 32 + t];
        out[(size_t)b * 32 + t] = s;
    }
}

__global__ void canary_kernel(const int* __restrict__ cntA, const int* __restrict__ flags,
                              const float* __restrict__ tau_p, int hostbits,
                              float* __restrict__ out) {
    __shared__ int ssum;
    int t = threadIdx.x;
    if (t == 0) ssum = 0;
    __syncthreads();
    int s = 0;
    for (int i = t; i < N_NODES; i += 256) s += cntA[i];
    atomicAdd(&ssum, s);
    __syncthreads();
    if (t == 0) {
        int bits = flags[0] | hostbits;
        if (ssum != N3) bits |= 16;
        if (fabsf(tau_p[0] - 0.1f) > 1e-6f) bits |= 32;
        if (bits) out[0] = 100000.0f * (float)bits;
    }
}

__global__ void ws_fail_kernel(float* out) {
    if (threadIdx.x == 0 && blockIdx.x == 0) out[0] = 100000.0f;
}

// ---------------------------------------------------------------------------
extern "C" void kernel_launch(void* const* d_in, const int* in_sizes, int n_in,
                              void* d_out, int out_size, void* d_ws, size_t ws_size,
                              hipStream_t stream) {
    const float* x      = (const float*)d_in[0];
    const float* tau    = (const float*)d_in[1];
    const float* L      = (const float*)d_in[2];
    const float* K0     = (const float*)d_in[3];
    const float* K1     = (const float*)d_in[4];
    const float* Wself  = (const float*)d_in[5];
    const float* Wneigh = (const float*)d_in[6];
    const float* bconv  = (const float*)d_in[7];
    const float* W1     = (const float*)d_in[8];
    const float* b1     = (const float*)d_in[9];
    const float* W2     = (const float*)d_in[10];
    const float* b2     = (const float*)d_in[11];
    float* out = (float*)d_out;

    char* ws = (char*)d_ws;
    size_t off = 0;
    int* flags = (int*)(ws + off); off += 256;    // [0]=hard [2..4]=nA,nB,nC
    int* cntA  = (int*)(ws + off); off += 32768;
    int* cntB  = (int*)(ws + off); off += 32768;
    int* cntC  = (int*)(ws + off); off += 32768;
    float* uA = (float*)(ws + off); off += (size_t)N_NODES * 32 * 4;    // 1 MB
    float* g1 = (float*)(ws + off); off += (size_t)N_NODES * 64 * 4;    // 2 MB
    float* uB = (float*)(ws + off); off += (size_t)N_NODES * 64 * 4;    // 2 MB
    float* g2 = (float*)(ws + off); off += (size_t)N_NODES * 128 * 4;   // 4 MB
    size_t zero_bytes = off;                      // ~9.3 MB, zeroed per call
    int* n32   = (int*)(ws + off); off += 32768;
    int* s32   = (int*)(ws + off); off += 65536;
    int* listA = (int*)(ws + off); off += 32768;
    int* listB = (int*)(ws + off); off += 32768;
    int* listC = (int*)(ws + off); off += 32768;
    float* z   = (float*)(ws + off); off += (size_t)N1 * 192 * 4;
    const size_t needed = off;

    if (ws_size < needed) {
        ws_fail_kernel<<<1, 64, 0, stream>>>(out);
        return;
    }
    int hostbits = 0;
    if (n_in != 14) hostbits |= 64;
    if (out_size != 32768) hostbits |= 256;

    // fast zero of accumulation region (replaces 152-us runtime memset)
    zero_ws<<<2048, 256, 0, stream>>>((float4*)d_ws, (int)(zero_bytes / 16));
    convert_idx<<<128, 256, 0, stream>>>(d_in[12], d_in[13], n32, s32, flags);
    count_kernel<<<24, 256, 0, stream>>>(n32, cntA, cntB, cntC);
    compact_kernel<<<32, 256, 0, stream>>>(cntA, cntB, cntC, listA, listB, listC,
                                           flags + 2);

    // diffusion: pA = L[rows]@x ; uA = cntA*(x - tau*pA)
    rows_f32s<32, 0><<<dim3(128, KSL, 1), 256, 0, stream>>>(L, L, x, listA, flags + 2,
                                                            0, uA);
    ep0_kernel<<<1024, 256, 0, stream>>>(x, tau, cntA, uA);
    // hop1: g1 = [K0|K1][rows]@uA ; uB = cntB*g1
    rows_f32s<32, 1><<<dim3(128, KSL, 2), 256, 0, stream>>>(K0, K1, uA, listB, flags + 2,
                                                            1, g1);
    ep1_kernel<<<2048, 256, 0, stream>>>(cntB, g1, uB);
    // hop2: g2 = [K0|K1][rows]@uB
    rows_f32s<64, 2><<<dim3(128, KSL, 2), 256, 0, stream>>>(K0, K1, uB, listC, flags + 2,
                                                            2, g2);
    z_kernel<<<1536, 256, 0, stream>>>(g1, g2, n32, z);
    head_kernel<<<1024, 256, 0, stream>>>(z, s32, Wself, Wneigh, bconv, W1, b1, W2, b2,
                                          out);
    canary_kernel<<<1, 256, 0, stream>>>(cntA, flags, tau, hostbits, out);
}